// Round 16
// baseline (121.164 us; speedup 1.0000x reference)
//
#include <hip/hip_runtime.h>

typedef unsigned short u16;
typedef unsigned int u32;

#define B_   4
#define C_   256
#define CI_  128
#define H_   64
#define W_   64
#define NPB_ 4096     // pixels per batch image
#define NP_  16384    // total pixels
#define K_   9        // 3x3 taps
#define MROWS_ 272    // 128 q + 128 k + 1 wcomb + 15 pad

typedef __attribute__((ext_vector_type(8))) __bf16 bf16x8_t;
typedef __attribute__((ext_vector_type(4))) float f32x4_t;
typedef __attribute__((ext_vector_type(2))) float f32x2_t;
typedef __attribute__((ext_vector_type(4))) u32 u32x4;

// forced-issue global load (k1): volatile asm order is preserved.
#define GLD(dst, p, immstr) \
    asm volatile("global_load_dwordx4 %0, %1, off offset:" immstr \
                 : "=v"(dst) : "v"(p))
#define KEEP(v) asm volatile("" :: "v"(v))

__device__ __forceinline__ float bf2f_lo(u32 w) {
    union { u32 i; float f; } x; x.i = w << 16; return x.f;
}
__device__ __forceinline__ float bf2f_hi(u32 w) {
    union { u32 i; float f; } x; x.i = w & 0xffff0000u; return x.f;
}
__device__ __forceinline__ u16 f2bf(float f) {  // round-to-nearest-even
    union { float f; u32 i; } x; x.f = f;
    u32 lsb = (x.i >> 16) & 1u;
    return (u16)((x.i + 0x7fffu + lsb) >> 16);
}
// packed bilinear accumulate: 8 bf16 channels, f32x2 lanes -> v_pk_fma_f32
__device__ __forceinline__ void acc8p(f32x2_t* f, uint4 v, f32x2_t w2) {
    f32x2_t p;
    p.x = bf2f_lo(v.x); p.y = bf2f_hi(v.x); f[0] += w2 * p;
    p.x = bf2f_lo(v.y); p.y = bf2f_hi(v.y); f[1] += w2 * p;
    p.x = bf2f_lo(v.z); p.y = bf2f_hi(v.z); f[2] += w2 * p;
    p.x = bf2f_lo(v.w); p.y = bf2f_hi(v.w); f[3] += w2 * p;
}

// k0b: prepare Wt in FRAGMENT-TILED layout + bias[272]. (unchanged)
__global__ void k0b_prep(const float* __restrict__ Wq, const float* __restrict__ bq,
                         const float* __restrict__ Wk, const float* __restrict__ bk,
                         const float* __restrict__ Wv, const float* __restrict__ bv,
                         const float* __restrict__ Wo,
                         u16* __restrict__ Wt, float* __restrict__ bias) {
    const int o = blockIdx.x;   // 0..271 (row)
    const int c = threadIdx.x;  // 0..255 (channel)
    u16 val;
    if (o < 128) {
        val = f2bf(Wq[o * C_ + c]);
        if (c == 0) bias[o] = bq[o];
    } else if (o < 256) {
        val = f2bf(Wk[(o - 128) * C_ + c]);
        if (c == 0) bias[o] = bk[o - 128];
    } else if (o == 256) {
        float s = 0.f;
        #pragma unroll 8
        for (int oo = 0; oo < CI_; ++oo)
            s += Wo[oo] * Wv[oo * C_ + c];
        val = f2bf(s);
        if (c == 0) {
            float ts = 0.f;
            #pragma unroll 8
            for (int oo = 0; oo < CI_; ++oo) ts += Wo[oo] * bv[oo];
            bias[256] = ts;
        }
    } else {
        val = 0;
        if (c == 0) bias[o] = 0.f;
    }
    const int mt = o >> 4, l16 = o & 15;
    const int kk = c >> 5, g = (c >> 3) & 3, e = c & 7;
    Wt[(size_t)((mt * 8 + kk) * 64 + g * 16 + l16) * 8 + e] = val;
}

// k1: MFMA GEMM (r13 structure). THIS ROUND: x staged via 2x float4 loads per
// thread (was 8 scalar strided) and xs stride 276 u16 (138 dw -> bank-rotating,
// 2-way = free). D map: col(px)=l&15, row=(l>>4)*4+r (m89).
__global__ __launch_bounds__(512) void k1_proj(
    const float* __restrict__ x, const u16* __restrict__ Wt,
    const float* __restrict__ bias,
    u16* __restrict__ qk, float* __restrict__ vs) {
    __shared__ u16 xs[16][276];
    const int t = threadIdx.x;
    const int l = t & 63;
    const int w = t >> 6;
    const int lane16 = l & 15;
    const int g = l >> 4;
    const int p0 = blockIdx.x * 16;
    const int b = p0 >> 12;
    const int pin = p0 & 4095;

    const int mts[3] = {2 * w, 2 * w + 1, 16};

    // ---- forced-issue ALL 24 A-fragment loads ----
    u32x4 afr[8][3];
    #pragma unroll
    for (int n = 0; n < 3; ++n) {
        const u16* pA = Wt + ((size_t)(mts[n] * 8) * 64 + l) * 8;
        const u16* pB = pA + 4 * 64 * 8;
        GLD(afr[0][n], pA, "0");    GLD(afr[1][n], pA, "1024");
        GLD(afr[2][n], pA, "2048"); GLD(afr[3][n], pA, "3072");
        GLD(afr[4][n], pB, "0");    GLD(afr[5][n], pB, "1024");
        GLD(afr[6][n], pB, "2048"); GLD(afr[7][n], pB, "3072");
    }

    {   // stage x: thread t -> channels {2c2, 2c2+1}, pixel quad (t&3)*4
        const int c2 = t >> 2;              // 0..127
        const int pq = (t & 3) * 4;
        const float* s0 = x + (size_t)(b * C_ + 2 * c2) * NPB_ + pin + pq;
        const float4 va = *reinterpret_cast<const float4*>(s0);
        const float4 vb = *reinterpret_cast<const float4*>(s0 + NPB_);
        *reinterpret_cast<u32*>(&xs[pq + 0][2 * c2]) = (u32)f2bf(va.x) | ((u32)f2bf(vb.x) << 16);
        *reinterpret_cast<u32*>(&xs[pq + 1][2 * c2]) = (u32)f2bf(va.y) | ((u32)f2bf(vb.y) << 16);
        *reinterpret_cast<u32*>(&xs[pq + 2][2 * c2]) = (u32)f2bf(va.z) | ((u32)f2bf(vb.z) << 16);
        *reinterpret_cast<u32*>(&xs[pq + 3][2 * c2]) = (u32)f2bf(va.w) | ((u32)f2bf(vb.w) << 16);
    }
    __syncthreads();
    asm volatile("s_waitcnt vmcnt(0)" ::: "memory");
    __builtin_amdgcn_sched_barrier(0);

    f32x4_t acc[3];
    #pragma unroll
    for (int n = 0; n < 3; ++n)
        #pragma unroll
        for (int r = 0; r < 4; ++r)
            acc[n][r] = bias[mts[n] * 16 + g * 4 + r];

    #pragma unroll
    for (int kk = 0; kk < 8; ++kk) {
        const bf16x8_t bv = *reinterpret_cast<const bf16x8_t*>(&xs[lane16][kk * 32 + g * 8]);
        #pragma unroll
        for (int n = 0; n < 3; ++n) {
            const bf16x8_t av = __builtin_bit_cast(bf16x8_t, afr[kk][n]);
            acc[n] = __builtin_amdgcn_mfma_f32_16x16x32_bf16(av, bv, acc[n], 0, 0, 0);
        }
    }

    // epilogue
    const int px = p0 + lane16;
    u16* qrow = qk + (size_t)px * C_;
    #pragma unroll
    for (int n = 0; n < 2; ++n) {
        const int mt = mts[n];
        u32* dst = reinterpret_cast<u32*>(qrow + mt * 16 + g * 4);
        dst[0] = (u32)f2bf(acc[n][0]) | ((u32)f2bf(acc[n][1]) << 16);
        dst[1] = (u32)f2bf(acc[n][2]) | ((u32)f2bf(acc[n][3]) << 16);
    }
    if (w == 0 && g == 0) vs[px] = acc[2][0];
}

// shared geometry helper for k2 family
__device__ __forceinline__ void k2_geom(
    const float* off, int b, int rem, int y, int xx, int tap,
    float* wgt, int* ppc) {
    const float* offb = off + ((size_t)b * (2 * K_) + 2 * tap) * NPB_ + rem;
    const float oy = offb[0];
    const float ox = offb[NPB_];
    const float py = (float)(y + tap / 3 - 1) + oy;
    const float px = (float)(xx + tap % 3 - 1) + ox;
    const float fy0 = floorf(py), fx0 = floorf(px);
    const float fy = py - fy0, fx = px - fx0;
    const int y0 = (int)fy0, x0 = (int)fx0;
    #pragma unroll
    for (int c = 0; c < 4; ++c) {
        const int dy = c >> 1, dx = c & 1;
        const int yi = y0 + dy, xi = x0 + dx;
        const float wv = (dy ? fy : 1.f - fy) * (dx ? fx : 1.f - fx);
        const int ok = (yi >= 0) & (yi < H_) & (xi >= 0) & (xi < W_);
        const int yc = min(max(yi, 0), H_ - 1);
        const int xc = min(max(xi, 0), W_ - 1);
        ppc[c] = yc * W_ + xc;
        wgt[c] = ok ? wv : 0.f;
    }
}

// PROBE 0: geometry + the 32 gather loads ONLY (results kept live, no stores).
__global__ __launch_bounds__(256) void k2_p0(
    const float* __restrict__ off, const u16* __restrict__ qk,
    const float* __restrict__ vs) {
    const int t = threadIdx.x;
    const int l = t & 63;
    const int bid = blockIdx.x;
    const int swz = (bid & 7) * ((int)gridDim.x >> 3) + (bid >> 3);
    const int pixel = swz * 4 + (t >> 6);
    const int b = pixel >> 12;
    const int rem = pixel & 4095;
    const int y = rem >> 6, xx = rem & 63;
    const int l16 = l & 15;
    const int tap = (l16 < K_) ? l16 : (K_ - 1);
    const int g = l >> 4;

    float wgt[4]; int ppc[4];
    k2_geom(off, b, rem, y, xx, tap, wgt, ppc);
    const u16* qkb = qk + ((size_t)(b << 12)) * C_ + g * 8;
    const float* vsm = vs + (b << 12);

    u32 acc = 0;
    float fa = 0.f;
    #pragma unroll
    for (int c = 0; c < 4; ++c) {
        const u16* p = qkb + (size_t)ppc[c] * C_;
        #pragma unroll
        for (int s = 0; s < 4; ++s) {
            const uint4 qv = *reinterpret_cast<const uint4*>(p + s * 32);
            const uint4 kv = *reinterpret_cast<const uint4*>(p + CI_ + s * 32);
            acc ^= qv.x ^ qv.y ^ qv.z ^ qv.w ^ kv.x ^ kv.y ^ kv.z ^ kv.w;
        }
        fa += wgt[c] * vsm[ppc[c]];
    }
    KEEP(acc); KEEP(fa);
}

// PROBE 2: FULL compute pipeline, but all 4 corners read the CENTER pixel's
// row (coalesced, L1-hot); real weights. No stores (keep-alive).
__global__ __launch_bounds__(256) void k2_p2(
    const float* __restrict__ off, const u16* __restrict__ qk,
    const float* __restrict__ vs, const float* __restrict__ bo) {
    const int t = threadIdx.x;
    const int l = t & 63;
    const int bid = blockIdx.x;
    const int swz = (bid & 7) * ((int)gridDim.x >> 3) + (bid >> 3);
    const int pixel = swz * 4 + (t >> 6);
    const int b = pixel >> 12;
    const int rem = pixel & 4095;
    const int y = rem >> 6, xx = rem & 63;
    const int l16 = l & 15;
    const int tap = (l16 < K_) ? l16 : (K_ - 1);
    const int g = l >> 4;

    float wgt[4]; int ppc[4];
    k2_geom(off, b, rem, y, xx, tap, wgt, ppc);
    #pragma unroll
    for (int c = 0; c < 4; ++c) ppc[c] = rem;      // <-- center row (coalesced)
    const u16* qkb = qk + ((size_t)(b << 12)) * C_ + g * 8;
    const float* vsm = vs + (b << 12);

    uint4 qv[4][4], kv[4][4];
    #pragma unroll
    for (int c = 0; c < 4; ++c) {
        const u16* p = qkb + (size_t)ppc[c] * C_;
        #pragma unroll
        for (int s = 0; s < 4; ++s) {
            qv[c][s] = *reinterpret_cast<const uint4*>(p + s * 32);
            kv[c][s] = *reinterpret_cast<const uint4*>(p + CI_ + s * 32);
        }
    }
    float vsu_t = 0.f;
    #pragma unroll
    for (int c = 0; c < 4; ++c) vsu_t += wgt[c] * vsm[ppc[c]];

    f32x2_t fq[16], fk[16];
    #pragma unroll
    for (int e = 0; e < 16; ++e) { fq[e] = (f32x2_t){0.f, 0.f}; fk[e] = (f32x2_t){0.f, 0.f}; }
    #pragma unroll
    for (int s = 0; s < 4; ++s)
        #pragma unroll
        for (int c = 0; c < 4; ++c) {
            const f32x2_t w2 = {wgt[c], wgt[c]};
            acc8p(&fq[s * 4], qv[c][s], w2);
            acc8p(&fk[s * 4], kv[c][s], w2);
        }

    f32x4_t acc = {0.f, 0.f, 0.f, 0.f};
    #pragma unroll
    for (int s = 0; s < 4; ++s) {
        bf16x8_t av, bv;
        #pragma unroll
        for (int e = 0; e < 4; ++e) {
            av[2 * e]     = (__bf16)fk[s * 4 + e].x;
            av[2 * e + 1] = (__bf16)fk[s * 4 + e].y;
            bv[2 * e]     = (__bf16)fq[s * 4 + e].x;
            bv[2 * e + 1] = (__bf16)fq[s * 4 + e].y;
        }
        acc = __builtin_amdgcn_mfma_f32_16x16x32_bf16(av, bv, acc, 0, 0, 0);
    }

    float mx = -1e30f;
    #pragma unroll
    for (int r = 0; r < 4; ++r) {
        const int j = g * 4 + r;
        if (j < K_) mx = fmaxf(mx, acc[r]);
    }
    mx = fmaxf(mx, __shfl_xor(mx, 16, 64));
    mx = fmaxf(mx, __shfl_xor(mx, 32, 64));
    float vj[4];
    #pragma unroll
    for (int r = 0; r < 4; ++r) vj[r] = __shfl(vsu_t, g * 4 + r, 64);
    float den = 0.f, num = 0.f;
    #pragma unroll
    for (int r = 0; r < 4; ++r) {
        const int j = g * 4 + r;
        if (j < K_) {
            const float e = __expf(acc[r] - mx);
            den += e;
            num += e * vj[r];
        }
    }
    den += __shfl_xor(den, 16, 64); den += __shfl_xor(den, 32, 64);
    num += __shfl_xor(num, 16, 64); num += __shfl_xor(num, 32, 64);
    const float z = num / den + bo[0];
    const float o = 1.f / (1.f + __expf(-z));
    KEEP(o);
}

// k2 REAL: r9's exact passing kernel (branchless clamped gather, up-front
// C loads, XCD swizzle). A/B share (lane,elem)->k map (HW k-perm cancels);
// C/D: col=l&15, row=(l>>4)*4+reg (m89).
__global__ __launch_bounds__(256) void k2_attn(
    const float* __restrict__ off, const u16* __restrict__ qk,
    const float* __restrict__ vs, const float* __restrict__ bo,
    float* __restrict__ out) {
    const int t = threadIdx.x;
    const int l = t & 63;
    const int bid = blockIdx.x;
    const int swz = (bid & 7) * ((int)gridDim.x >> 3) + (bid >> 3);
    const int pixel = swz * 4 + (t >> 6);
    const int b = pixel >> 12;
    const int rem = pixel & 4095;
    const int y = rem >> 6, xx = rem & 63;
    const int l16 = l & 15;
    const int tap = (l16 < K_) ? l16 : (K_ - 1);
    const int g = l >> 4;

    float wgt[4]; int ppc[4];
    k2_geom(off, b, rem, y, xx, tap, wgt, ppc);
    const u16* qkb = qk + ((size_t)(b << 12)) * C_ + g * 8;
    const float* vsm = vs + (b << 12);

    uint4 qv[4][4], kv[4][4];
    #pragma unroll
    for (int c = 0; c < 4; ++c) {
        const u16* p = qkb + (size_t)ppc[c] * C_;
        #pragma unroll
        for (int s = 0; s < 4; ++s) {
            qv[c][s] = *reinterpret_cast<const uint4*>(p + s * 32);
            kv[c][s] = *reinterpret_cast<const uint4*>(p + CI_ + s * 32);
        }
    }
    float vsu_t = 0.f;
    #pragma unroll
    for (int c = 0; c < 4; ++c) vsu_t += wgt[c] * vsm[ppc[c]];

    f32x2_t fq[16], fk[16];
    #pragma unroll
    for (int e = 0; e < 16; ++e) { fq[e] = (f32x2_t){0.f, 0.f}; fk[e] = (f32x2_t){0.f, 0.f}; }
    #pragma unroll
    for (int s = 0; s < 4; ++s)
        #pragma unroll
        for (int c = 0; c < 4; ++c) {
            const f32x2_t w2 = {wgt[c], wgt[c]};
            acc8p(&fq[s * 4], qv[c][s], w2);
            acc8p(&fk[s * 4], kv[c][s], w2);
        }

    f32x4_t acc = {0.f, 0.f, 0.f, 0.f};
    #pragma unroll
    for (int s = 0; s < 4; ++s) {
        bf16x8_t av, bv;
        #pragma unroll
        for (int e = 0; e < 4; ++e) {
            av[2 * e]     = (__bf16)fk[s * 4 + e].x;   // A = ku (rows j)
            av[2 * e + 1] = (__bf16)fk[s * 4 + e].y;
            bv[2 * e]     = (__bf16)fq[s * 4 + e].x;   // B = qu (cols i)
            bv[2 * e + 1] = (__bf16)fq[s * 4 + e].y;
        }
        acc = __builtin_amdgcn_mfma_f32_16x16x32_bf16(av, bv, acc, 0, 0, 0);
    }

    float mx = -1e30f;
    #pragma unroll
    for (int r = 0; r < 4; ++r) {
        const int j = g * 4 + r;
        if (j < K_) mx = fmaxf(mx, acc[r]);
    }
    mx = fmaxf(mx, __shfl_xor(mx, 16, 64));
    mx = fmaxf(mx, __shfl_xor(mx, 32, 64));

    float vj[4];
    #pragma unroll
    for (int r = 0; r < 4; ++r) vj[r] = __shfl(vsu_t, g * 4 + r, 64);

    float den = 0.f, num = 0.f;
    #pragma unroll
    for (int r = 0; r < 4; ++r) {
        const int j = g * 4 + r;
        if (j < K_) {
            const float e = __expf(acc[r] - mx);
            den += e;
            num += e * vj[r];
        }
    }
    den += __shfl_xor(den, 16, 64); den += __shfl_xor(den, 32, 64);
    num += __shfl_xor(num, 16, 64); num += __shfl_xor(num, 32, 64);

    if (l < K_) {
        const float z = num / den + bo[0];
        out[(size_t)b * K_ * NPB_ + (size_t)l * NPB_ + rem] = 1.f / (1.f + __expf(-z));
    }
}

extern "C" void kernel_launch(void* const* d_in, const int* in_sizes, int n_in,
                              void* d_out, int out_size, void* d_ws, size_t ws_size,
                              hipStream_t stream) {
    const float* x   = (const float*)d_in[0];
    const float* off = (const float*)d_in[1];
    const float* Wq  = (const float*)d_in[2];
    const float* bq  = (const float*)d_in[3];
    const float* Wk  = (const float*)d_in[4];
    const float* bk  = (const float*)d_in[5];
    const float* Wv  = (const float*)d_in[6];
    const float* bv  = (const float*)d_in[7];
    const float* Wo  = (const float*)d_in[8];
    const float* bo  = (const float*)d_in[9];
    float* out = (float*)d_out;

    char* ws = (char*)d_ws;
    u16*   qkbuf = (u16*)(ws + 4096);                 // 16384*256 bf16 = 8 MiB
    float* vsmap = (float*)(ws + 4096 + 8388608);     // 16384 f32
    u16*   Wt    = (u16*)(ws + 4096 + 8388608 + 65536);
    float* bias  = (float*)(ws + 4096 + 8388608 + 65536 + 139264);

    k0b_prep<<<MROWS_, 256, 0, stream>>>(Wq, bq, Wk, bk, Wv, bv, Wo, Wt, bias);
    k1_proj<<<NP_ / 16, 512, 0, stream>>>(x, Wt, bias, qkbuf, vsmap);
    k2_p0<<<NP_ / 4, 256, 0, stream>>>(off, qkbuf, vsmap);
    k2_p2<<<NP_ / 4, 256, 0, stream>>>(off, qkbuf, vsmap, bo);
    k2_attn<<<NP_ / 4, 256, 0, stream>>>(off, qkbuf, vsmap, bo, out);
}